// Round 11
// baseline (4030.850 us; speedup 1.0000x reference)
//
#include <hip/hip_runtime.h>
#include <cstddef>

// Problem constants (fixed by the reference)
static const int WW = 8192;     // width (atoms)
static const int DD = 768;      // input dim
static const int BBATCH = 8192; // batch
static const int KSEL = 32;     // MP steps

// ---------------------------------------------------------------------------
// column norms of Ad [D, W] -> nrm[W] = max(||Ad[:,w]||, 1e-8), fp64 accumulate
// ---------------------------------------------------------------------------
__global__ __launch_bounds__(256) void colnorm_kernel(const float* __restrict__ Ad,
                                                      float* __restrict__ nrm) {
    int w = blockIdx.x * 256 + threadIdx.x;
    double s = 0.0;
    for (int d = 0; d < DD; ++d) {
        double v = (double)Ad[(size_t)d * WW + w];
        s += v * v;
    }
    nrm[w] = fmaxf((float)sqrt(s), 1e-8f);
}

// ---------------------------------------------------------------------------
// AdnT[w, d] = Ad[d, w] / nrm[w]   (LDS tiled transpose, 32x32)
// ---------------------------------------------------------------------------
__global__ __launch_bounds__(256) void transpose_scale_kernel(const float* __restrict__ Ad,
                                                              const float* __restrict__ nrm,
                                                              float* __restrict__ AdnT) {
    __shared__ float tile[32][33];
    int wb = blockIdx.x * 32;
    int db = blockIdx.y * 32;
    int tx = threadIdx.x;   // 0..31
    int ty = threadIdx.y;   // 0..7
    for (int i = ty; i < 32; i += 8)
        tile[i][tx] = Ad[(size_t)(db + i) * WW + (wb + tx)];
    __syncthreads();
    for (int i = ty; i < 32; i += 8)
        AdnT[(size_t)(wb + i) * DD + (db + tx)] = tile[tx][i] / nrm[wb + i];
}

// ---------------------------------------------------------------------------
// R11: Gram f32 reverted to the R9-exact config (measured best: 880 us @
// 66.4% VALUBusy, occupancy 31.7). 128x64 tile, BK=16, 8x4 microtile,
// ~52 VGPR. R10's 128x128/8x8 variant regressed (956 us, occupancy 20) —
// 64-reg accumulator trades occupancy/ILP for amortization at a loss.
// Upper-region blocks only (bx >= 2*by); mirror fills strict-lower tiles.
// ---------------------------------------------------------------------------
__global__ __launch_bounds__(256) void gram_tn_f32_kernel(const float* __restrict__ Ad,
                                                          const float* __restrict__ nrm,
                                                          float* __restrict__ G) {
    const int bx = blockIdx.x, by = blockIdx.y;
    if (bx < 2 * by) return;   // block entirely strictly-lower -> skip
    __shared__ __align__(16) float As[16 * 132];   // As[k][i], i=0..127 (pad 4)
    __shared__ __align__(16) float Bs[16 * 66];    // Bs[k][j], j=0..63  (pad 2)
    const int tid = threadIdx.x;
    const int tx = tid & 15;         // 0..15 (col group)
    const int ty = tid >> 4;         // 0..15 (row group)
    const int i0 = by * 128;
    const int j0 = bx * 64;
    const int ar0 = tid >> 6;        // 0..3
    const int ap0 = (tid & 63) * 2;  // 0..126
    const int brow = tid >> 5;       // 0..7
    const int bpos = (tid & 31) * 2; // 0..62

    float acc[8][4];
#pragma unroll
    for (int i = 0; i < 8; ++i)
#pragma unroll
        for (int j = 0; j < 4; ++j) acc[i][j] = 0.0f;

    for (int k0 = 0; k0 < DD; k0 += 16) {
        float2 aL[4];
#pragma unroll
        for (int q = 0; q < 4; ++q)
            aL[q] = *(const float2*)&Ad[(size_t)(k0 + 4 * q + ar0) * WW + i0 + ap0];
        float2 bl0 = *(const float2*)&Ad[(size_t)(k0 + brow) * WW + j0 + bpos];
        float2 bl1 = *(const float2*)&Ad[(size_t)(k0 + 8 + brow) * WW + j0 + bpos];
        __syncthreads();   // previous iteration's LDS reads done
#pragma unroll
        for (int q = 0; q < 4; ++q)
            *(float2*)&As[(4 * q + ar0) * 132 + ap0] = aL[q];
        *(float2*)&Bs[brow * 66 + bpos] = bl0;
        *(float2*)&Bs[(8 + brow) * 66 + bpos] = bl1;
        __syncthreads();

#pragma unroll
        for (int kk = 0; kk < 16; ++kk) {
            const float* arw = &As[kk * 132];
            const float* bb = &Bs[kk * 66];
            float4 a0 = *(const float4*)&arw[ty * 4];        // broadcast reads
            float4 a1 = *(const float4*)&arw[64 + ty * 4];
            float av[8] = {a0.x, a0.y, a0.z, a0.w, a1.x, a1.y, a1.z, a1.w};
            float bv[4] = {bb[tx], bb[16 + tx], bb[32 + tx], bb[48 + tx]};
#pragma unroll
            for (int i = 0; i < 8; ++i)
#pragma unroll
                for (int j = 0; j < 4; ++j) acc[i][j] += av[i] * bv[j];
        }
    }

#pragma unroll
    for (int band = 0; band < 2; ++band) {
#pragma unroll
        for (int i = 0; i < 4; ++i) {
            int row = i0 + band * 64 + ty * 4 + i;
            double inv_i = 1.0 / (double)nrm[row];
            int ar = band * 4 + i;
#pragma unroll
            for (int j = 0; j < 4; ++j) {
                int col = j0 + j * 16 + tx;
                G[(size_t)row * WW + col] = (float)((double)acc[ar][j] * inv_i / (double)nrm[col]);
            }
        }
    }
}

// ---------------------------------------------------------------------------
// mirror: G[j,i] = G[i,j] for strict-upper 64x64 tiles
// ---------------------------------------------------------------------------
__global__ __launch_bounds__(256) void mirror_kernel(float* __restrict__ G) {
    const int ti = blockIdx.y;
    const int tj = blockIdx.x;
    if (tj <= ti) return;
    __shared__ float tile[64][65];
    const int t = threadIdx.x;
    const int c4 = (t & 15) * 4;   // 0..60
    const int r  = t >> 4;         // 0..15
#pragma unroll
    for (int rr = r; rr < 64; rr += 16) {
        float4 v = *(const float4*)&G[(size_t)(ti * 64 + rr) * WW + tj * 64 + c4];
        tile[rr][c4 + 0] = v.x;
        tile[rr][c4 + 1] = v.y;
        tile[rr][c4 + 2] = v.z;
        tile[rr][c4 + 3] = v.w;
    }
    __syncthreads();
#pragma unroll
    for (int rr = r; rr < 64; rr += 16) {
        float4 v = make_float4(tile[c4 + 0][rr], tile[c4 + 1][rr],
                               tile[c4 + 2][rr], tile[c4 + 3][rr]);
        *(float4*)&G[(size_t)(tj * 64 + rr) * WW + ti * 64 + c4] = v;
    }
}

// ---------------------------------------------------------------------------
// z f32, BK=32 (R10 config — kept: the working half of the R10 bundle,
// ~-80 us vs BK16). 128x64 tile, 8x4 microtile, same output mapping/grid
// as R9 (512 blocks per 512-row chunk). Per-element FMA order unchanged
// (k ascending) -> Z bitwise-identical to R9/R10. LDS 25.3 KB.
// ---------------------------------------------------------------------------
__global__ __launch_bounds__(256) void z_nn_f32_kernel(const float* __restrict__ X,
                                                       const float* __restrict__ Ad,
                                                       const float* __restrict__ bd,
                                                       const float* __restrict__ nrm,
                                                       float* __restrict__ Z) {
    __shared__ __align__(16) float As[32 * 132];   // As[k][b], b=0..127 (pad 4)
    __shared__ __align__(16) float Bs[32 * 66];    // Bs[k][w], w=0..63  (pad 2)
    const int tid = threadIdx.x;
    const int tx = tid & 15;
    const int ty = tid >> 4;
    const int b0 = blockIdx.y * 128;
    const int w0 = blockIdx.x * 64;
    const int r   = tid >> 1;         // 0..127 (A staging batch-row)
    const int k16 = (tid & 1) * 16;   // 0 or 16 (A staging k offset)
    const int brow = tid >> 5;        // 0..7
    const int bpos = (tid & 31) * 2;  // 0..62

    float acc[8][4];
#pragma unroll
    for (int i = 0; i < 8; ++i)
#pragma unroll
        for (int j = 0; j < 4; ++j) acc[i][j] = 0.0f;

    for (int k0 = 0; k0 < DD; k0 += 32) {
        float4 aV[4];
#pragma unroll
        for (int c = 0; c < 4; ++c) {
            float4 bias = *(const float4*)&bd[k0 + k16 + 4 * c];
            float4 a = *(const float4*)&X[(size_t)(b0 + r) * DD + k0 + k16 + 4 * c];
            a.x -= bias.x; a.y -= bias.y; a.z -= bias.z; a.w -= bias.w;
            aV[c] = a;
        }
        float2 bV[4];
#pragma unroll
        for (int s = 0; s < 4; ++s)
            bV[s] = *(const float2*)&Ad[(size_t)(k0 + 8 * s + brow) * WW + w0 + bpos];
        __syncthreads();   // previous iteration's LDS reads done
#pragma unroll
        for (int c = 0; c < 4; ++c) {
            As[(k16 + 4 * c + 0) * 132 + r] = aV[c].x;
            As[(k16 + 4 * c + 1) * 132 + r] = aV[c].y;
            As[(k16 + 4 * c + 2) * 132 + r] = aV[c].z;
            As[(k16 + 4 * c + 3) * 132 + r] = aV[c].w;
        }
#pragma unroll
        for (int s = 0; s < 4; ++s)
            *(float2*)&Bs[(8 * s + brow) * 66 + bpos] = bV[s];
        __syncthreads();

#pragma unroll
        for (int kk = 0; kk < 32; ++kk) {
            const float* arw = &As[kk * 132];
            const float* bb = &Bs[kk * 66];
            float4 a0 = *(const float4*)&arw[ty * 4];
            float4 a1 = *(const float4*)&arw[64 + ty * 4];
            float av[8] = {a0.x, a0.y, a0.z, a0.w, a1.x, a1.y, a1.z, a1.w};
            float bv[4] = {bb[tx], bb[16 + tx], bb[32 + tx], bb[48 + tx]};
#pragma unroll
            for (int i = 0; i < 8; ++i)
#pragma unroll
                for (int j = 0; j < 4; ++j) acc[i][j] += av[i] * bv[j];
        }
    }

#pragma unroll
    for (int band = 0; band < 2; ++band) {
#pragma unroll
        for (int i = 0; i < 4; ++i) {
            int row = b0 + band * 64 + ty * 4 + i;
            int ar = band * 4 + i;
#pragma unroll
            for (int j = 0; j < 4; ++j) {
                int col = w0 + j * 16 + tx;
                Z[(size_t)row * WW + col] = (float)((double)acc[ar][j] / (double)nrm[col]);
            }
        }
    }
}

// ---------------------------------------------------------------------------
// Fused MP loop (R4/R9 version, verbatim). One block per batch row; z-row in
// LDS for all 32 steps. mp is L3-BW-bound (~1.05 ms total at ~7.7 TB/s
// effective; measured invariant to pairing/reg-residency) -> at its floor.
// ---------------------------------------------------------------------------
__global__ __launch_bounds__(256) void mp_loop_kernel(const float* __restrict__ z0,
                                                      const float* __restrict__ G,
                                                      int* __restrict__ idxL,
                                                      float* __restrict__ valL) {
    __shared__ __align__(16) float zrow[WW];   // 32 KB
    __shared__ float wv[4];
    __shared__ int   wi[4];
    const int b = blockIdx.x;
    const int t = threadIdx.x;
    float4* zs = (float4*)zrow;

    float best = -1.f;
    int bidx = 0;
    unsigned selmask = 0;   // bit j*4+e: slot (t+256*j) element e is selected

    {
        const float4* zp = (const float4*)(z0 + (size_t)b * WW);
#pragma unroll
        for (int j = 0; j < 8; ++j) {
            int slot = t + 256 * j;
            float4 v = zp[slot];
            zs[slot] = v;
            int w = slot * 4;
            float a0 = fabsf(v.x), a1 = fabsf(v.y), a2 = fabsf(v.z), a3 = fabsf(v.w);
            if (a0 > best) { best = a0; bidx = w; }
            if (a1 > best) { best = a1; bidx = w + 1; }
            if (a2 > best) { best = a2; bidx = w + 2; }
            if (a3 > best) { best = a3; bidx = w + 3; }
        }
    }

    for (int k = 0; k < KSEL; ++k) {
        float v = best;
        int i = bidx;
#pragma unroll
        for (int off = 32; off > 0; off >>= 1) {
            float ov = __shfl_xor(v, off, 64);
            int   oi = __shfl_xor(i, off, 64);
            if (ov > v || (ov == v && oi < i)) { v = ov; i = oi; }
        }
        if ((t & 63) == 0) { wv[t >> 6] = v; wi[t >> 6] = i; }
        __syncthreads();   // A: partials visible; prev phase's zrow writes visible
        float rv = wv[0];
        int   ri = wi[0];
#pragma unroll
        for (int q = 1; q < 4; ++q) {
            float qv = wv[q];
            int   qi = wi[q];
            if (qv > rv || (qv == rv && qi < ri)) { rv = qv; ri = qi; }
        }
        const int idx = ri;
        const float val = zrow[idx];   // pre-update value (LDS broadcast)
        if (t == 0) {
            idxL[(size_t)b * KSEL + k] = idx;
            valL[(size_t)b * KSEL + k] = val;
        }
        if (((idx >> 2) & 255) == t)
            selmask |= 1u << (((idx >> 10) << 2) | (idx & 3));
        if (k == KSEL - 1) break;      // final update is dead work
        __syncthreads();   // B: all threads have read val before zrow changes

        best = -1.f;
        bidx = 0;
        const float4* gr = (const float4*)(G + (size_t)idx * WW);
#pragma unroll
        for (int j = 0; j < 8; ++j) {
            int slot = t + 256 * j;
            float4 g = gr[slot];
            float4 z = zs[slot];
            unsigned m = (selmask >> (j * 4)) & 0xFu;
            float n0 = (m & 1u) ? 0.f : z.x - val * g.x;
            float n1 = (m & 2u) ? 0.f : z.y - val * g.y;
            float n2 = (m & 4u) ? 0.f : z.z - val * g.z;
            float n3 = (m & 8u) ? 0.f : z.w - val * g.w;
            zs[slot] = make_float4(n0, n1, n2, n3);
            int w = slot * 4;
            float a0 = fabsf(n0), a1 = fabsf(n1), a2 = fabsf(n2), a3 = fabsf(n3);
            if (a0 > best) { best = a0; bidx = w; }
            if (a1 > best) { best = a1; bidx = w + 1; }
            if (a2 > best) { best = a2; bidx = w + 2; }
            if (a3 > best) { best = a3; bidx = w + 3; }
        }
    }
}

// ---------------------------------------------------------------------------
// copy idx/val metadata (d_out staging -> ws), element-wise
// ---------------------------------------------------------------------------
__global__ __launch_bounds__(256) void copy_meta_kernel(const int* __restrict__ si,
                                                        const float* __restrict__ sv,
                                                        int* __restrict__ di,
                                                        float* __restrict__ dv,
                                                        int n) {
    int i = blockIdx.x * 256 + threadIdx.x;
    if (i < n) {
        di[i] = si[i];
        dv[i] = sv[i];
    }
}

// ---------------------------------------------------------------------------
// out[row, :] = bd + sum_k val[b,k] * AdnT[idx[b,k], :]
// ---------------------------------------------------------------------------
__global__ __launch_bounds__(256) void assemble_kernel(const float* __restrict__ AdnT,
                                                       const float* __restrict__ bd,
                                                       const int* __restrict__ idxL,
                                                       const float* __restrict__ valL,
                                                       float* __restrict__ out,
                                                       int rowStart) {
    __shared__ int sidx[KSEL];
    __shared__ float sval[KSEL];
    const int b = blockIdx.x;
    const int row = rowStart + b;
    const int t = threadIdx.x;
    if (t < KSEL) {
        sidx[t] = idxL[(size_t)b * KSEL + t];
        sval[t] = valL[(size_t)b * KSEL + t];
    }
    __syncthreads();
    float acc0 = bd[t];
    float acc1 = bd[t + 256];
    float acc2 = bd[t + 512];
#pragma unroll 4
    for (int k = 0; k < KSEL; ++k) {
        const float* col = AdnT + (size_t)sidx[k] * DD;
        float v = sval[k];
        acc0 += v * col[t];
        acc1 += v * col[t + 256];
        acc2 += v * col[t + 512];
    }
    out[(size_t)row * DD + t] = acc0;
    out[(size_t)row * DD + t + 256] = acc1;
    out[(size_t)row * DD + t + 512] = acc2;
}

// ---------------------------------------------------------------------------
extern "C" void kernel_launch(void* const* d_in, const int* in_sizes, int n_in,
                              void* d_out, int out_size, void* d_ws, size_t ws_size,
                              hipStream_t stream) {
    const float* x  = (const float*)d_in[0];   // [B, D]
    const float* Ad = (const float*)d_in[1];   // [D, W]
    const float* bd = (const float*)d_in[2];   // [1, D]
    float* out = (float*)d_out;                // [B, D]

    const size_t ADNT_B = (size_t)WW * DD * 4;        // 25,165,824
    const size_t NRM_B  = (size_t)WW * 4;             // 32,768
    const size_t IDX_B  = (size_t)BBATCH * KSEL * 4;  // 1,048,576
    const size_t VAL_B  = IDX_B;
    const size_t G_B    = (size_t)WW * WW * 4;        // 268,435,456 (= 256 MiB)
    const size_t ZROW_B = (size_t)WW * 4;             // 32,768
    const size_t A_MIN  = ADNT_B + NRM_B + IDX_B + VAL_B + G_B + 128 * ZROW_B;

    if (ws_size >= A_MIN) {
        // ---------------- Layout A: everything in ws ----------------
        char* p = (char*)d_ws;
        float* AdnT = (float*)p;  p += ADNT_B;
        float* nrm  = (float*)p;  p += NRM_B;
        int*   idxL = (int*)p;    p += IDX_B;
        float* valL = (float*)p;  p += VAL_B;
        float* G    = (float*)p;  p += G_B;
        float* z    = (float*)p;
        size_t z_avail = ws_size - (ADNT_B + NRM_B + IDX_B + VAL_B + G_B);
        int chunk = (int)((z_avail / ZROW_B) / 128) * 128;
        if (chunk > BBATCH) chunk = BBATCH;

        colnorm_kernel<<<WW / 256, 256, 0, stream>>>(Ad, nrm);
        gram_tn_f32_kernel<<<dim3(WW / 64, WW / 128), 256, 0, stream>>>(Ad, nrm, G);
        mirror_kernel<<<dim3(WW / 64, WW / 64), 256, 0, stream>>>(G);
        for (int r0 = 0; r0 < BBATCH; r0 += chunk) {
            int rows = (BBATCH - r0 < chunk) ? (BBATCH - r0) : chunk;
            z_nn_f32_kernel<<<dim3(WW / 64, rows / 128), 256, 0, stream>>>(
                x + (size_t)r0 * DD, Ad, bd, nrm, z);
            mp_loop_kernel<<<rows, 256, 0, stream>>>(
                z, G, idxL + (size_t)r0 * KSEL, valL + (size_t)r0 * KSEL);
        }
        transpose_scale_kernel<<<dim3(WW / 32, DD / 32), dim3(32, 8), 0, stream>>>(Ad, nrm, AdnT);
        assemble_kernel<<<BBATCH, 256, 0, stream>>>(AdnT, bd, idxL, valL, out, 0);
    } else if (ws_size >= G_B) {
        // ---------------- Layout B: ws = G only; scratch in d_out ----------------
        // d_out carve (25,165,824 B total):
        //   [0 .. 20,971,520)          z chunks (512 rows x 32 KB used)
        //   [20,971,520 .. 21,004,288) nrm (32 KB)
        //   [23,068,672 .. 24,117,248) idxL [B,32]
        //   [24,117,248 .. 25,165,824) valL [B,32]
        float* G    = (float*)d_ws;
        char*  ob   = (char*)d_out;
        float* z    = (float*)ob;
        float* nrm  = (float*)(ob + 20971520);
        int*   idxL = (int*)(ob + 23068672);
        float* valL = (float*)(ob + 24117248);
        // after MP loops, G is dead -> reuse ws:
        float* AdnT = (float*)d_ws;
        int*   idx2 = (int*)((char*)d_ws + ADNT_B);
        float* val2 = (float*)((char*)d_ws + ADNT_B + IDX_B);
        const int chunk = 512;   // 4 x 128 rows -> 512 mp blocks = exactly 2/CU

        colnorm_kernel<<<WW / 256, 256, 0, stream>>>(Ad, nrm);
        gram_tn_f32_kernel<<<dim3(WW / 64, WW / 128), 256, 0, stream>>>(Ad, nrm, G);
        mirror_kernel<<<dim3(WW / 64, WW / 64), 256, 0, stream>>>(G);
        for (int r0 = 0; r0 < BBATCH; r0 += chunk) {
            int rows = (BBATCH - r0 < chunk) ? (BBATCH - r0) : chunk;
            z_nn_f32_kernel<<<dim3(WW / 64, rows / 128), 256, 0, stream>>>(
                x + (size_t)r0 * DD, Ad, bd, nrm, z);
            mp_loop_kernel<<<rows, 256, 0, stream>>>(
                z, G, idxL + (size_t)r0 * KSEL, valL + (size_t)r0 * KSEL);
        }
        {
            int n = BBATCH * KSEL;
            copy_meta_kernel<<<(n + 255) / 256, 256, 0, stream>>>(idxL, valL, idx2, val2, n);
        }
        transpose_scale_kernel<<<dim3(WW / 32, DD / 32), dim3(32, 8), 0, stream>>>(Ad, nrm, AdnT);
        assemble_kernel<<<BBATCH, 256, 0, stream>>>(AdnT, bd, idx2, val2, out, 0);
    }
    // else: ws too small for any fp32-G plan -> leave output zeroed (clean fail)
}

// Round 12
// 3738.855 us; speedup vs baseline: 1.0781x; 1.0781x over previous
//
#include <hip/hip_runtime.h>
#include <cstddef>

// Problem constants (fixed by the reference)
static const int WW = 8192;     // width (atoms)
static const int DD = 768;      // input dim
static const int BBATCH = 8192; // batch
static const int KSEL = 32;     // MP steps

// ---------------------------------------------------------------------------
// column norms of Ad [D, W] -> nrm[W] = max(||Ad[:,w]||, 1e-8), fp64 accumulate
// ---------------------------------------------------------------------------
__global__ __launch_bounds__(256) void colnorm_kernel(const float* __restrict__ Ad,
                                                      float* __restrict__ nrm) {
    int w = blockIdx.x * 256 + threadIdx.x;
    double s = 0.0;
    for (int d = 0; d < DD; ++d) {
        double v = (double)Ad[(size_t)d * WW + w];
        s += v * v;
    }
    nrm[w] = fmaxf((float)sqrt(s), 1e-8f);
}

// ---------------------------------------------------------------------------
// AdnT[w, d] = Ad[d, w] / nrm[w]   (LDS tiled transpose, 32x32)
// ---------------------------------------------------------------------------
__global__ __launch_bounds__(256) void transpose_scale_kernel(const float* __restrict__ Ad,
                                                              const float* __restrict__ nrm,
                                                              float* __restrict__ AdnT) {
    __shared__ float tile[32][33];
    int wb = blockIdx.x * 32;
    int db = blockIdx.y * 32;
    int tx = threadIdx.x;   // 0..31
    int ty = threadIdx.y;   // 0..7
    for (int i = ty; i < 32; i += 8)
        tile[i][tx] = Ad[(size_t)(db + i) * WW + (wb + tx)];
    __syncthreads();
    for (int i = ty; i < 32; i += 8)
        AdnT[(size_t)(wb + i) * DD + (db + tx)] = tile[tx][i] / nrm[wb + i];
}

// ---------------------------------------------------------------------------
// R12: Gram f32, column microtile remapped col = j*16+tx -> tx*4+j.
// R11 audit: 6 LDS ops/kk (2 b128 + 4 scalar b32) = ~47 LDS-pipe cycles per
// 64 FMA cycles -> LDS pipe ~64% busy alongside VALU ~65% (dual contention).
// Contiguous B-fragment: one ds_read_b128 at bb[tx*4] (3 LDS ops/kk, ~36
// cyc, -23%) + single coalesced float4 store per thread in the epilogue.
// Bs stride 66->68 floats (272B = 16-aligned rows). Per-element FMA chain
// unchanged -> G bitwise-identical to R11. 128x64, BK=16, 8x4 microtile.
// Upper-region blocks only (bx >= 2*by); mirror fills strict-lower tiles.
// ---------------------------------------------------------------------------
__global__ __launch_bounds__(256) void gram_tn_f32_kernel(const float* __restrict__ Ad,
                                                          const float* __restrict__ nrm,
                                                          float* __restrict__ G) {
    const int bx = blockIdx.x, by = blockIdx.y;
    if (bx < 2 * by) return;   // block entirely strictly-lower -> skip
    __shared__ __align__(16) float As[16 * 132];   // As[k][i], i=0..127 (pad 4)
    __shared__ __align__(16) float Bs[16 * 68];    // Bs[k][j], j=0..63  (pad 4)
    const int tid = threadIdx.x;
    const int tx = tid & 15;         // 0..15 (col group; cols tx*4..tx*4+3)
    const int ty = tid >> 4;         // 0..15 (row group)
    const int i0 = by * 128;
    const int j0 = bx * 64;
    const int ar0 = tid >> 6;        // 0..3
    const int ap0 = (tid & 63) * 2;  // 0..126
    const int brow = tid >> 5;       // 0..7
    const int bpos = (tid & 31) * 2; // 0..62

    float acc[8][4];
#pragma unroll
    for (int i = 0; i < 8; ++i)
#pragma unroll
        for (int j = 0; j < 4; ++j) acc[i][j] = 0.0f;

    for (int k0 = 0; k0 < DD; k0 += 16) {
        float2 aL[4];
#pragma unroll
        for (int q = 0; q < 4; ++q)
            aL[q] = *(const float2*)&Ad[(size_t)(k0 + 4 * q + ar0) * WW + i0 + ap0];
        float2 bl0 = *(const float2*)&Ad[(size_t)(k0 + brow) * WW + j0 + bpos];
        float2 bl1 = *(const float2*)&Ad[(size_t)(k0 + 8 + brow) * WW + j0 + bpos];
        __syncthreads();   // previous iteration's LDS reads done
#pragma unroll
        for (int q = 0; q < 4; ++q)
            *(float2*)&As[(4 * q + ar0) * 132 + ap0] = aL[q];
        *(float2*)&Bs[brow * 68 + bpos] = bl0;
        *(float2*)&Bs[(8 + brow) * 68 + bpos] = bl1;
        __syncthreads();

#pragma unroll
        for (int kk = 0; kk < 16; ++kk) {
            const float* arw = &As[kk * 132];
            const float* bb = &Bs[kk * 68];
            float4 a0 = *(const float4*)&arw[ty * 4];        // broadcast reads
            float4 a1 = *(const float4*)&arw[64 + ty * 4];
            float4 bq = *(const float4*)&bb[tx * 4];         // contiguous b128
            float av[8] = {a0.x, a0.y, a0.z, a0.w, a1.x, a1.y, a1.z, a1.w};
            float bv[4] = {bq.x, bq.y, bq.z, bq.w};
#pragma unroll
            for (int i = 0; i < 8; ++i)
#pragma unroll
                for (int j = 0; j < 4; ++j) acc[i][j] += av[i] * bv[j];
        }
    }

#pragma unroll
    for (int band = 0; band < 2; ++band) {
#pragma unroll
        for (int i = 0; i < 4; ++i) {
            int row = i0 + band * 64 + ty * 4 + i;
            double inv_i = 1.0 / (double)nrm[row];
            int ar = band * 4 + i;
            int colb = j0 + tx * 4;
            float4 o;
            o.x = (float)((double)acc[ar][0] * inv_i / (double)nrm[colb + 0]);
            o.y = (float)((double)acc[ar][1] * inv_i / (double)nrm[colb + 1]);
            o.z = (float)((double)acc[ar][2] * inv_i / (double)nrm[colb + 2]);
            o.w = (float)((double)acc[ar][3] * inv_i / (double)nrm[colb + 3]);
            *(float4*)&G[(size_t)row * WW + colb] = o;
        }
    }
}

// ---------------------------------------------------------------------------
// mirror: G[j,i] = G[i,j] for strict-upper 64x64 tiles
// ---------------------------------------------------------------------------
__global__ __launch_bounds__(256) void mirror_kernel(float* __restrict__ G) {
    const int ti = blockIdx.y;
    const int tj = blockIdx.x;
    if (tj <= ti) return;
    __shared__ float tile[64][65];
    const int t = threadIdx.x;
    const int c4 = (t & 15) * 4;   // 0..60
    const int r  = t >> 4;         // 0..15
#pragma unroll
    for (int rr = r; rr < 64; rr += 16) {
        float4 v = *(const float4*)&G[(size_t)(ti * 64 + rr) * WW + tj * 64 + c4];
        tile[rr][c4 + 0] = v.x;
        tile[rr][c4 + 1] = v.y;
        tile[rr][c4 + 2] = v.z;
        tile[rr][c4 + 3] = v.w;
    }
    __syncthreads();
#pragma unroll
    for (int rr = r; rr < 64; rr += 16) {
        float4 v = make_float4(tile[c4 + 0][rr], tile[c4 + 1][rr],
                               tile[c4 + 2][rr], tile[c4 + 3][rr]);
        *(float4*)&G[(size_t)(tj * 64 + rr) * WW + ti * 64 + c4] = v;
    }
}

// ---------------------------------------------------------------------------
// R12: z f32, BK=32, same column remap as gram (col = tx*4+j): B-fragment as
// one ds_read_b128, float4 output store. Bs stride 68 (16B-aligned rows).
// Per-element FMA chain unchanged -> Z bitwise-identical to R11.
// 128x64 tile, 8x4 microtile, 512 blocks per 512-row chunk.
// ---------------------------------------------------------------------------
__global__ __launch_bounds__(256) void z_nn_f32_kernel(const float* __restrict__ X,
                                                       const float* __restrict__ Ad,
                                                       const float* __restrict__ bd,
                                                       const float* __restrict__ nrm,
                                                       float* __restrict__ Z) {
    __shared__ __align__(16) float As[32 * 132];   // As[k][b], b=0..127 (pad 4)
    __shared__ __align__(16) float Bs[32 * 68];    // Bs[k][w], w=0..63  (pad 4)
    const int tid = threadIdx.x;
    const int tx = tid & 15;
    const int ty = tid >> 4;
    const int b0 = blockIdx.y * 128;
    const int w0 = blockIdx.x * 64;
    const int r   = tid >> 1;         // 0..127 (A staging batch-row)
    const int k16 = (tid & 1) * 16;   // 0 or 16 (A staging k offset)
    const int brow = tid >> 5;        // 0..7
    const int bpos = (tid & 31) * 2;  // 0..62

    float acc[8][4];
#pragma unroll
    for (int i = 0; i < 8; ++i)
#pragma unroll
        for (int j = 0; j < 4; ++j) acc[i][j] = 0.0f;

    for (int k0 = 0; k0 < DD; k0 += 32) {
        float4 aV[4];
#pragma unroll
        for (int c = 0; c < 4; ++c) {
            float4 bias = *(const float4*)&bd[k0 + k16 + 4 * c];
            float4 a = *(const float4*)&X[(size_t)(b0 + r) * DD + k0 + k16 + 4 * c];
            a.x -= bias.x; a.y -= bias.y; a.z -= bias.z; a.w -= bias.w;
            aV[c] = a;
        }
        float2 bV[4];
#pragma unroll
        for (int s = 0; s < 4; ++s)
            bV[s] = *(const float2*)&Ad[(size_t)(k0 + 8 * s + brow) * WW + w0 + bpos];
        __syncthreads();   // previous iteration's LDS reads done
#pragma unroll
        for (int c = 0; c < 4; ++c) {
            As[(k16 + 4 * c + 0) * 132 + r] = aV[c].x;
            As[(k16 + 4 * c + 1) * 132 + r] = aV[c].y;
            As[(k16 + 4 * c + 2) * 132 + r] = aV[c].z;
            As[(k16 + 4 * c + 3) * 132 + r] = aV[c].w;
        }
#pragma unroll
        for (int s = 0; s < 4; ++s)
            *(float2*)&Bs[(8 * s + brow) * 68 + bpos] = bV[s];
        __syncthreads();

#pragma unroll
        for (int kk = 0; kk < 32; ++kk) {
            const float* arw = &As[kk * 132];
            const float* bb = &Bs[kk * 68];
            float4 a0 = *(const float4*)&arw[ty * 4];
            float4 a1 = *(const float4*)&arw[64 + ty * 4];
            float4 bq = *(const float4*)&bb[tx * 4];
            float av[8] = {a0.x, a0.y, a0.z, a0.w, a1.x, a1.y, a1.z, a1.w};
            float bv[4] = {bq.x, bq.y, bq.z, bq.w};
#pragma unroll
            for (int i = 0; i < 8; ++i)
#pragma unroll
                for (int j = 0; j < 4; ++j) acc[i][j] += av[i] * bv[j];
        }
    }

#pragma unroll
    for (int band = 0; band < 2; ++band) {
#pragma unroll
        for (int i = 0; i < 4; ++i) {
            int row = b0 + band * 64 + ty * 4 + i;
            int ar = band * 4 + i;
            int colb = w0 + tx * 4;
            float4 o;
            o.x = (float)((double)acc[ar][0] / (double)nrm[colb + 0]);
            o.y = (float)((double)acc[ar][1] / (double)nrm[colb + 1]);
            o.z = (float)((double)acc[ar][2] / (double)nrm[colb + 2]);
            o.w = (float)((double)acc[ar][3] / (double)nrm[colb + 3]);
            *(float4*)&Z[(size_t)row * WW + colb] = o;
        }
    }
}

// ---------------------------------------------------------------------------
// Fused MP loop (R4/R9 version, verbatim). One block per batch row; z-row in
// LDS for all 32 steps. mp is L3-BW-bound (~1.05 ms total; measured
// invariant to pairing/reg-residency) -> at its floor.
// ---------------------------------------------------------------------------
__global__ __launch_bounds__(256) void mp_loop_kernel(const float* __restrict__ z0,
                                                      const float* __restrict__ G,
                                                      int* __restrict__ idxL,
                                                      float* __restrict__ valL) {
    __shared__ __align__(16) float zrow[WW];   // 32 KB
    __shared__ float wv[4];
    __shared__ int   wi[4];
    const int b = blockIdx.x;
    const int t = threadIdx.x;
    float4* zs = (float4*)zrow;

    float best = -1.f;
    int bidx = 0;
    unsigned selmask = 0;   // bit j*4+e: slot (t+256*j) element e is selected

    {
        const float4* zp = (const float4*)(z0 + (size_t)b * WW);
#pragma unroll
        for (int j = 0; j < 8; ++j) {
            int slot = t + 256 * j;
            float4 v = zp[slot];
            zs[slot] = v;
            int w = slot * 4;
            float a0 = fabsf(v.x), a1 = fabsf(v.y), a2 = fabsf(v.z), a3 = fabsf(v.w);
            if (a0 > best) { best = a0; bidx = w; }
            if (a1 > best) { best = a1; bidx = w + 1; }
            if (a2 > best) { best = a2; bidx = w + 2; }
            if (a3 > best) { best = a3; bidx = w + 3; }
        }
    }

    for (int k = 0; k < KSEL; ++k) {
        float v = best;
        int i = bidx;
#pragma unroll
        for (int off = 32; off > 0; off >>= 1) {
            float ov = __shfl_xor(v, off, 64);
            int   oi = __shfl_xor(i, off, 64);
            if (ov > v || (ov == v && oi < i)) { v = ov; i = oi; }
        }
        if ((t & 63) == 0) { wv[t >> 6] = v; wi[t >> 6] = i; }
        __syncthreads();   // A: partials visible; prev phase's zrow writes visible
        float rv = wv[0];
        int   ri = wi[0];
#pragma unroll
        for (int q = 1; q < 4; ++q) {
            float qv = wv[q];
            int   qi = wi[q];
            if (qv > rv || (qv == rv && qi < ri)) { rv = qv; ri = qi; }
        }
        const int idx = ri;
        const float val = zrow[idx];   // pre-update value (LDS broadcast)
        if (t == 0) {
            idxL[(size_t)b * KSEL + k] = idx;
            valL[(size_t)b * KSEL + k] = val;
        }
        if (((idx >> 2) & 255) == t)
            selmask |= 1u << (((idx >> 10) << 2) | (idx & 3));
        if (k == KSEL - 1) break;      // final update is dead work
        __syncthreads();   // B: all threads have read val before zrow changes

        best = -1.f;
        bidx = 0;
        const float4* gr = (const float4*)(G + (size_t)idx * WW);
#pragma unroll
        for (int j = 0; j < 8; ++j) {
            int slot = t + 256 * j;
            float4 g = gr[slot];
            float4 z = zs[slot];
            unsigned m = (selmask >> (j * 4)) & 0xFu;
            float n0 = (m & 1u) ? 0.f : z.x - val * g.x;
            float n1 = (m & 2u) ? 0.f : z.y - val * g.y;
            float n2 = (m & 4u) ? 0.f : z.z - val * g.z;
            float n3 = (m & 8u) ? 0.f : z.w - val * g.w;
            zs[slot] = make_float4(n0, n1, n2, n3);
            int w = slot * 4;
            float a0 = fabsf(n0), a1 = fabsf(n1), a2 = fabsf(n2), a3 = fabsf(n3);
            if (a0 > best) { best = a0; bidx = w; }
            if (a1 > best) { best = a1; bidx = w + 1; }
            if (a2 > best) { best = a2; bidx = w + 2; }
            if (a3 > best) { best = a3; bidx = w + 3; }
        }
    }
}

// ---------------------------------------------------------------------------
// copy idx/val metadata (d_out staging -> ws), element-wise
// ---------------------------------------------------------------------------
__global__ __launch_bounds__(256) void copy_meta_kernel(const int* __restrict__ si,
                                                        const float* __restrict__ sv,
                                                        int* __restrict__ di,
                                                        float* __restrict__ dv,
                                                        int n) {
    int i = blockIdx.x * 256 + threadIdx.x;
    if (i < n) {
        di[i] = si[i];
        dv[i] = sv[i];
    }
}

// ---------------------------------------------------------------------------
// out[row, :] = bd + sum_k val[b,k] * AdnT[idx[b,k], :]
// ---------------------------------------------------------------------------
__global__ __launch_bounds__(256) void assemble_kernel(const float* __restrict__ AdnT,
                                                       const float* __restrict__ bd,
                                                       const int* __restrict__ idxL,
                                                       const float* __restrict__ valL,
                                                       float* __restrict__ out,
                                                       int rowStart) {
    __shared__ int sidx[KSEL];
    __shared__ float sval[KSEL];
    const int b = blockIdx.x;
    const int row = rowStart + b;
    const int t = threadIdx.x;
    if (t < KSEL) {
        sidx[t] = idxL[(size_t)b * KSEL + t];
        sval[t] = valL[(size_t)b * KSEL + t];
    }
    __syncthreads();
    float acc0 = bd[t];
    float acc1 = bd[t + 256];
    float acc2 = bd[t + 512];
#pragma unroll 4
    for (int k = 0; k < KSEL; ++k) {
        const float* col = AdnT + (size_t)sidx[k] * DD;
        float v = sval[k];
        acc0 += v * col[t];
        acc1 += v * col[t + 256];
        acc2 += v * col[t + 512];
    }
    out[(size_t)row * DD + t] = acc0;
    out[(size_t)row * DD + t + 256] = acc1;
    out[(size_t)row * DD + t + 512] = acc2;
}

// ---------------------------------------------------------------------------
extern "C" void kernel_launch(void* const* d_in, const int* in_sizes, int n_in,
                              void* d_out, int out_size, void* d_ws, size_t ws_size,
                              hipStream_t stream) {
    const float* x  = (const float*)d_in[0];   // [B, D]
    const float* Ad = (const float*)d_in[1];   // [D, W]
    const float* bd = (const float*)d_in[2];   // [1, D]
    float* out = (float*)d_out;                // [B, D]

    const size_t ADNT_B = (size_t)WW * DD * 4;        // 25,165,824
    const size_t NRM_B  = (size_t)WW * 4;             // 32,768
    const size_t IDX_B  = (size_t)BBATCH * KSEL * 4;  // 1,048,576
    const size_t VAL_B  = IDX_B;
    const size_t G_B    = (size_t)WW * WW * 4;        // 268,435,456 (= 256 MiB)
    const size_t ZROW_B = (size_t)WW * 4;             // 32,768
    const size_t A_MIN  = ADNT_B + NRM_B + IDX_B + VAL_B + G_B + 128 * ZROW_B;

    if (ws_size >= A_MIN) {
        // ---------------- Layout A: everything in ws ----------------
        char* p = (char*)d_ws;
        float* AdnT = (float*)p;  p += ADNT_B;
        float* nrm  = (float*)p;  p += NRM_B;
        int*   idxL = (int*)p;    p += IDX_B;
        float* valL = (float*)p;  p += VAL_B;
        float* G    = (float*)p;  p += G_B;
        float* z    = (float*)p;
        size_t z_avail = ws_size - (ADNT_B + NRM_B + IDX_B + VAL_B + G_B);
        int chunk = (int)((z_avail / ZROW_B) / 128) * 128;
        if (chunk > BBATCH) chunk = BBATCH;

        colnorm_kernel<<<WW / 256, 256, 0, stream>>>(Ad, nrm);
        gram_tn_f32_kernel<<<dim3(WW / 64, WW / 128), 256, 0, stream>>>(Ad, nrm, G);
        mirror_kernel<<<dim3(WW / 64, WW / 64), 256, 0, stream>>>(G);
        for (int r0 = 0; r0 < BBATCH; r0 += chunk) {
            int rows = (BBATCH - r0 < chunk) ? (BBATCH - r0) : chunk;
            z_nn_f32_kernel<<<dim3(WW / 64, rows / 128), 256, 0, stream>>>(
                x + (size_t)r0 * DD, Ad, bd, nrm, z);
            mp_loop_kernel<<<rows, 256, 0, stream>>>(
                z, G, idxL + (size_t)r0 * KSEL, valL + (size_t)r0 * KSEL);
        }
        transpose_scale_kernel<<<dim3(WW / 32, DD / 32), dim3(32, 8), 0, stream>>>(Ad, nrm, AdnT);
        assemble_kernel<<<BBATCH, 256, 0, stream>>>(AdnT, bd, idxL, valL, out, 0);
    } else if (ws_size >= G_B) {
        // ---------------- Layout B: ws = G only; scratch in d_out ----------------
        // d_out carve (25,165,824 B total):
        //   [0 .. 20,971,520)          z chunks (512 rows x 32 KB used)
        //   [20,971,520 .. 21,004,288) nrm (32 KB)
        //   [23,068,672 .. 24,117,248) idxL [B,32]
        //   [24,117,248 .. 25,165,824) valL [B,32]
        float* G    = (float*)d_ws;
        char*  ob   = (char*)d_out;
        float* z    = (float*)ob;
        float* nrm  = (float*)(ob + 20971520);
        int*   idxL = (int*)(ob + 23068672);
        float* valL = (float*)(ob + 24117248);
        // after MP loops, G is dead -> reuse ws:
        float* AdnT = (float*)d_ws;
        int*   idx2 = (int*)((char*)d_ws + ADNT_B);
        float* val2 = (float*)((char*)d_ws + ADNT_B + IDX_B);
        const int chunk = 512;   // 4 x 128 rows -> 512 mp blocks = exactly 2/CU

        colnorm_kernel<<<WW / 256, 256, 0, stream>>>(Ad, nrm);
        gram_tn_f32_kernel<<<dim3(WW / 64, WW / 128), 256, 0, stream>>>(Ad, nrm, G);
        mirror_kernel<<<dim3(WW / 64, WW / 64), 256, 0, stream>>>(G);
        for (int r0 = 0; r0 < BBATCH; r0 += chunk) {
            int rows = (BBATCH - r0 < chunk) ? (BBATCH - r0) : chunk;
            z_nn_f32_kernel<<<dim3(WW / 64, rows / 128), 256, 0, stream>>>(
                x + (size_t)r0 * DD, Ad, bd, nrm, z);
            mp_loop_kernel<<<rows, 256, 0, stream>>>(
                z, G, idxL + (size_t)r0 * KSEL, valL + (size_t)r0 * KSEL);
        }
        {
            int n = BBATCH * KSEL;
            copy_meta_kernel<<<(n + 255) / 256, 256, 0, stream>>>(idxL, valL, idx2, val2, n);
        }
        transpose_scale_kernel<<<dim3(WW / 32, DD / 32), dim3(32, 8), 0, stream>>>(Ad, nrm, AdnT);
        assemble_kernel<<<BBATCH, 256, 0, stream>>>(AdnT, bd, idx2, val2, out, 0);
    }
    // else: ws too small for any fp32-G plan -> leave output zeroed (clean fail)
}

// Round 13
// 3668.174 us; speedup vs baseline: 1.0989x; 1.0193x over previous
//
#include <hip/hip_runtime.h>
#include <cstddef>

// Problem constants (fixed by the reference)
static const int WW = 8192;     // width (atoms)
static const int DD = 768;      // input dim
static const int BBATCH = 8192; // batch
static const int KSEL = 32;     // MP steps

// ---------------------------------------------------------------------------
// async global->LDS, 16 B per lane. LDS dest is wave-uniform base + lane*16
// (m104/m173); global src is per-lane. Loaded values identical to the manual
// path -> bitwise-identical results.
// ---------------------------------------------------------------------------
__device__ __forceinline__ void gll16(const float* g, float* l) {
    __builtin_amdgcn_global_load_lds(
        (const __attribute__((address_space(1))) unsigned int*)g,
        (__attribute__((address_space(3))) unsigned int*)l, 16, 0, 0);
}

// ---------------------------------------------------------------------------
// column norms of Ad [D, W] -> nrm[W] = max(||Ad[:,w]||, 1e-8), fp64 accumulate
// ---------------------------------------------------------------------------
__global__ __launch_bounds__(256) void colnorm_kernel(const float* __restrict__ Ad,
                                                      float* __restrict__ nrm) {
    int w = blockIdx.x * 256 + threadIdx.x;
    double s = 0.0;
    for (int d = 0; d < DD; ++d) {
        double v = (double)Ad[(size_t)d * WW + w];
        s += v * v;
    }
    nrm[w] = fmaxf((float)sqrt(s), 1e-8f);
}

// ---------------------------------------------------------------------------
// AdnT[w, d] = Ad[d, w] / nrm[w]   (LDS tiled transpose, 32x32)
// ---------------------------------------------------------------------------
__global__ __launch_bounds__(256) void transpose_scale_kernel(const float* __restrict__ Ad,
                                                              const float* __restrict__ nrm,
                                                              float* __restrict__ AdnT) {
    __shared__ float tile[32][33];
    int wb = blockIdx.x * 32;
    int db = blockIdx.y * 32;
    int tx = threadIdx.x;   // 0..31
    int ty = threadIdx.y;   // 0..7
    for (int i = ty; i < 32; i += 8)
        tile[i][tx] = Ad[(size_t)(db + i) * WW + (wb + tx)];
    __syncthreads();
    for (int i = ty; i < 32; i += 8)
        AdnT[(size_t)(wb + i) * DD + (db + tx)] = tile[tx][i] / nrm[wb + i];
}

// ---------------------------------------------------------------------------
// R13: Gram f32 with global_load_lds staging. R12 audit: much of VALUBusy
// (57.7%) is staging issue (6 float2 loads + 6 ds_writes + addr arith per
// K-step per thread). gll width=16 replaces it with 3 wave-issues/K-step.
// As [16][128] and Bs [16][64] UNPADDED (gll writes linearly): A-fragment
// reads are 4-address wave-broadcasts (stride-independent); B-fragment
// b128 reads at stride 64 are 2-way + broadcast = free (m136).
// FMA chains unchanged -> G bitwise-identical to R12. LDS 12.3 KB.
// 128x64 tile, BK=16, 8x4 microtile; bx >= 2*by skip + mirror.
// ---------------------------------------------------------------------------
__global__ __launch_bounds__(256) void gram_tn_f32_kernel(const float* __restrict__ Ad,
                                                          const float* __restrict__ nrm,
                                                          float* __restrict__ G) {
    const int bx = blockIdx.x, by = blockIdx.y;
    if (bx < 2 * by) return;   // block entirely strictly-lower -> skip
    __shared__ __align__(16) float As[16 * 128];   // As[k][i], linear
    __shared__ __align__(16) float Bs[16 * 64];    // Bs[k][j], linear
    const int tid = threadIdx.x;
    const int tx = tid & 15;         // 0..15 (col group; cols tx*4..tx*4+3)
    const int ty = tid >> 4;         // 0..15 (row group)
    const int wv = tid >> 6;         // wave 0..3
    const int ln = tid & 63;         // lane
    const int i0 = by * 128;
    const int j0 = bx * 64;
    // per-lane global offsets for gll chunks
    const int aRow = ln >> 5;          // 0..1 (within 2-row chunk)
    const int aCol = (ln & 31) * 4;    // 0..124
    const int bRow = ln >> 4;          // 0..3 (within 4-row chunk)
    const int bCol = (ln & 15) * 4;    // 0..60

    float acc[8][4];
#pragma unroll
    for (int i = 0; i < 8; ++i)
#pragma unroll
        for (int j = 0; j < 4; ++j) acc[i][j] = 0.0f;

    for (int k0 = 0; k0 < DD; k0 += 16) {
        __syncthreads();   // previous iteration's LDS reads done
        // A: 8 chunks of 2 rows; wave wv issues chunks 2wv, 2wv+1
#pragma unroll
        for (int s = 0; s < 2; ++s) {
            int c = 2 * wv + s;
            gll16(&Ad[(size_t)(k0 + 2 * c + aRow) * WW + i0 + aCol], &As[c * 256]);
        }
        // B: 4 chunks of 4 rows; wave wv issues chunk wv
        gll16(&Ad[(size_t)(k0 + 4 * wv + bRow) * WW + j0 + bCol], &Bs[wv * 256]);
        __syncthreads();   // (compiler drains vmcnt before barrier)

#pragma unroll
        for (int kk = 0; kk < 16; ++kk) {
            const float* arw = &As[kk * 128];
            const float* bb = &Bs[kk * 64];
            float4 a0 = *(const float4*)&arw[ty * 4];        // broadcast reads
            float4 a1 = *(const float4*)&arw[64 + ty * 4];
            float4 bq = *(const float4*)&bb[tx * 4];         // contiguous b128
            float av[8] = {a0.x, a0.y, a0.z, a0.w, a1.x, a1.y, a1.z, a1.w};
            float bv[4] = {bq.x, bq.y, bq.z, bq.w};
#pragma unroll
            for (int i = 0; i < 8; ++i)
#pragma unroll
                for (int j = 0; j < 4; ++j) acc[i][j] += av[i] * bv[j];
        }
    }

#pragma unroll
    for (int band = 0; band < 2; ++band) {
#pragma unroll
        for (int i = 0; i < 4; ++i) {
            int row = i0 + band * 64 + ty * 4 + i;
            double inv_i = 1.0 / (double)nrm[row];
            int ar = band * 4 + i;
            int colb = j0 + tx * 4;
            float4 o;
            o.x = (float)((double)acc[ar][0] * inv_i / (double)nrm[colb + 0]);
            o.y = (float)((double)acc[ar][1] * inv_i / (double)nrm[colb + 1]);
            o.z = (float)((double)acc[ar][2] * inv_i / (double)nrm[colb + 2]);
            o.w = (float)((double)acc[ar][3] * inv_i / (double)nrm[colb + 3]);
            *(float4*)&G[(size_t)row * WW + colb] = o;
        }
    }
}

// ---------------------------------------------------------------------------
// mirror: G[j,i] = G[i,j] for strict-upper 64x64 tiles
// ---------------------------------------------------------------------------
__global__ __launch_bounds__(256) void mirror_kernel(float* __restrict__ G) {
    const int ti = blockIdx.y;
    const int tj = blockIdx.x;
    if (tj <= ti) return;
    __shared__ float tile[64][65];
    const int t = threadIdx.x;
    const int c4 = (t & 15) * 4;   // 0..60
    const int r  = t >> 4;         // 0..15
#pragma unroll
    for (int rr = r; rr < 64; rr += 16) {
        float4 v = *(const float4*)&G[(size_t)(ti * 64 + rr) * WW + tj * 64 + c4];
        tile[rr][c4 + 0] = v.x;
        tile[rr][c4 + 1] = v.y;
        tile[rr][c4 + 2] = v.z;
        tile[rr][c4 + 3] = v.w;
    }
    __syncthreads();
#pragma unroll
    for (int rr = r; rr < 64; rr += 16) {
        float4 v = make_float4(tile[c4 + 0][rr], tile[c4 + 1][rr],
                               tile[c4 + 2][rr], tile[c4 + 3][rr]);
        *(float4*)&G[(size_t)(tj * 64 + rr) * WW + ti * 64 + c4] = v;
    }
}

// ---------------------------------------------------------------------------
// R13: z f32, BK=32. Bs staged via global_load_lds ([32][64] unpadded, 2
// chunks/wave); As keeps the reg-transpose path (transposed writes are
// incompatible with gll's linear destination). FMA chains unchanged -> Z
// bitwise-identical to R12. 128x64 tile, 8x4 microtile.
// ---------------------------------------------------------------------------
__global__ __launch_bounds__(256) void z_nn_f32_kernel(const float* __restrict__ X,
                                                       const float* __restrict__ Ad,
                                                       const float* __restrict__ bd,
                                                       const float* __restrict__ nrm,
                                                       float* __restrict__ Z) {
    __shared__ __align__(16) float As[32 * 132];   // As[k][b], b=0..127 (pad 4)
    __shared__ __align__(16) float Bs[32 * 64];    // Bs[k][w], linear
    const int tid = threadIdx.x;
    const int tx = tid & 15;
    const int ty = tid >> 4;
    const int wv = tid >> 6;
    const int ln = tid & 63;
    const int b0 = blockIdx.y * 128;
    const int w0 = blockIdx.x * 64;
    const int r   = tid >> 1;         // 0..127 (A staging batch-row)
    const int k16 = (tid & 1) * 16;   // 0 or 16 (A staging k offset)
    const int bRow = ln >> 4;         // 0..3 (within 4-row chunk)
    const int bCol = (ln & 15) * 4;   // 0..60

    float acc[8][4];
#pragma unroll
    for (int i = 0; i < 8; ++i)
#pragma unroll
        for (int j = 0; j < 4; ++j) acc[i][j] = 0.0f;

    for (int k0 = 0; k0 < DD; k0 += 32) {
        float4 aV[4];
#pragma unroll
        for (int c = 0; c < 4; ++c) {
            float4 bias = *(const float4*)&bd[k0 + k16 + 4 * c];
            float4 a = *(const float4*)&X[(size_t)(b0 + r) * DD + k0 + k16 + 4 * c];
            a.x -= bias.x; a.y -= bias.y; a.z -= bias.z; a.w -= bias.w;
            aV[c] = a;
        }
        __syncthreads();   // previous iteration's LDS reads done
        // B: 8 chunks of 4 rows; wave wv issues chunks 2wv, 2wv+1
#pragma unroll
        for (int s = 0; s < 2; ++s) {
            int c = 2 * wv + s;
            gll16(&Ad[(size_t)(k0 + 4 * c + bRow) * WW + w0 + bCol], &Bs[c * 256]);
        }
#pragma unroll
        for (int c = 0; c < 4; ++c) {
            As[(k16 + 4 * c + 0) * 132 + r] = aV[c].x;
            As[(k16 + 4 * c + 1) * 132 + r] = aV[c].y;
            As[(k16 + 4 * c + 2) * 132 + r] = aV[c].z;
            As[(k16 + 4 * c + 3) * 132 + r] = aV[c].w;
        }
        __syncthreads();   // (compiler drains vmcnt + lgkmcnt before barrier)

#pragma unroll
        for (int kk = 0; kk < 32; ++kk) {
            const float* arw = &As[kk * 132];
            const float* bb = &Bs[kk * 64];
            float4 a0 = *(const float4*)&arw[ty * 4];
            float4 a1 = *(const float4*)&arw[64 + ty * 4];
            float4 bq = *(const float4*)&bb[tx * 4];
            float av[8] = {a0.x, a0.y, a0.z, a0.w, a1.x, a1.y, a1.z, a1.w};
            float bv[4] = {bq.x, bq.y, bq.z, bq.w};
#pragma unroll
            for (int i = 0; i < 8; ++i)
#pragma unroll
                for (int j = 0; j < 4; ++j) acc[i][j] += av[i] * bv[j];
        }
    }

#pragma unroll
    for (int band = 0; band < 2; ++band) {
#pragma unroll
        for (int i = 0; i < 4; ++i) {
            int row = b0 + band * 64 + ty * 4 + i;
            int ar = band * 4 + i;
            int colb = w0 + tx * 4;
            float4 o;
            o.x = (float)((double)acc[ar][0] / (double)nrm[colb + 0]);
            o.y = (float)((double)acc[ar][1] / (double)nrm[colb + 1]);
            o.z = (float)((double)acc[ar][2] / (double)nrm[colb + 2]);
            o.w = (float)((double)acc[ar][3] / (double)nrm[colb + 3]);
            *(float4*)&Z[(size_t)row * WW + colb] = o;
        }
    }
}

// ---------------------------------------------------------------------------
// Fused MP loop (R4/R9 version, verbatim). One block per batch row; z-row in
// LDS for all 32 steps. mp is L3-BW-bound (~1.05 ms; measured invariant to
// pairing/reg-residency) -> at its floor.
// ---------------------------------------------------------------------------
__global__ __launch_bounds__(256) void mp_loop_kernel(const float* __restrict__ z0,
                                                      const float* __restrict__ G,
                                                      int* __restrict__ idxL,
                                                      float* __restrict__ valL) {
    __shared__ __align__(16) float zrow[WW];   // 32 KB
    __shared__ float wv[4];
    __shared__ int   wi[4];
    const int b = blockIdx.x;
    const int t = threadIdx.x;
    float4* zs = (float4*)zrow;

    float best = -1.f;
    int bidx = 0;
    unsigned selmask = 0;   // bit j*4+e: slot (t+256*j) element e is selected

    {
        const float4* zp = (const float4*)(z0 + (size_t)b * WW);
#pragma unroll
        for (int j = 0; j < 8; ++j) {
            int slot = t + 256 * j;
            float4 v = zp[slot];
            zs[slot] = v;
            int w = slot * 4;
            float a0 = fabsf(v.x), a1 = fabsf(v.y), a2 = fabsf(v.z), a3 = fabsf(v.w);
            if (a0 > best) { best = a0; bidx = w; }
            if (a1 > best) { best = a1; bidx = w + 1; }
            if (a2 > best) { best = a2; bidx = w + 2; }
            if (a3 > best) { best = a3; bidx = w + 3; }
        }
    }

    for (int k = 0; k < KSEL; ++k) {
        float v = best;
        int i = bidx;
#pragma unroll
        for (int off = 32; off > 0; off >>= 1) {
            float ov = __shfl_xor(v, off, 64);
            int   oi = __shfl_xor(i, off, 64);
            if (ov > v || (ov == v && oi < i)) { v = ov; i = oi; }
        }
        if ((t & 63) == 0) { wv[t >> 6] = v; wi[t >> 6] = i; }
        __syncthreads();   // A: partials visible; prev phase's zrow writes visible
        float rv = wv[0];
        int   ri = wi[0];
#pragma unroll
        for (int q = 1; q < 4; ++q) {
            float qv = wv[q];
            int   qi = wi[q];
            if (qv > rv || (qv == rv && qi < ri)) { rv = qv; ri = qi; }
        }
        const int idx = ri;
        const float val = zrow[idx];   // pre-update value (LDS broadcast)
        if (t == 0) {
            idxL[(size_t)b * KSEL + k] = idx;
            valL[(size_t)b * KSEL + k] = val;
        }
        if (((idx >> 2) & 255) == t)
            selmask |= 1u << (((idx >> 10) << 2) | (idx & 3));
        if (k == KSEL - 1) break;      // final update is dead work
        __syncthreads();   // B: all threads have read val before zrow changes

        best = -1.f;
        bidx = 0;
        const float4* gr = (const float4*)(G + (size_t)idx * WW);
#pragma unroll
        for (int j = 0; j < 8; ++j) {
            int slot = t + 256 * j;
            float4 g = gr[slot];
            float4 z = zs[slot];
            unsigned m = (selmask >> (j * 4)) & 0xFu;
            float n0 = (m & 1u) ? 0.f : z.x - val * g.x;
            float n1 = (m & 2u) ? 0.f : z.y - val * g.y;
            float n2 = (m & 4u) ? 0.f : z.z - val * g.z;
            float n3 = (m & 8u) ? 0.f : z.w - val * g.w;
            zs[slot] = make_float4(n0, n1, n2, n3);
            int w = slot * 4;
            float a0 = fabsf(n0), a1 = fabsf(n1), a2 = fabsf(n2), a3 = fabsf(n3);
            if (a0 > best) { best = a0; bidx = w; }
            if (a1 > best) { best = a1; bidx = w + 1; }
            if (a2 > best) { best = a2; bidx = w + 2; }
            if (a3 > best) { best = a3; bidx = w + 3; }
        }
    }
}

// ---------------------------------------------------------------------------
// copy idx/val metadata (d_out staging -> ws), element-wise
// ---------------------------------------------------------------------------
__global__ __launch_bounds__(256) void copy_meta_kernel(const int* __restrict__ si,
                                                        const float* __restrict__ sv,
                                                        int* __restrict__ di,
                                                        float* __restrict__ dv,
                                                        int n) {
    int i = blockIdx.x * 256 + threadIdx.x;
    if (i < n) {
        di[i] = si[i];
        dv[i] = sv[i];
    }
}

// ---------------------------------------------------------------------------
// out[row, :] = bd + sum_k val[b,k] * AdnT[idx[b,k], :]
// ---------------------------------------------------------------------------
__global__ __launch_bounds__(256) void assemble_kernel(const float* __restrict__ AdnT,
                                                       const float* __restrict__ bd,
                                                       const int* __restrict__ idxL,
                                                       const float* __restrict__ valL,
                                                       float* __restrict__ out,
                                                       int rowStart) {
    __shared__ int sidx[KSEL];
    __shared__ float sval[KSEL];
    const int b = blockIdx.x;
    const int row = rowStart + b;
    const int t = threadIdx.x;
    if (t < KSEL) {
        sidx[t] = idxL[(size_t)b * KSEL + t];
        sval[t] = valL[(size_t)b * KSEL + t];
    }
    __syncthreads();
    float acc0 = bd[t];
    float acc1 = bd[t + 256];
    float acc2 = bd[t + 512];
#pragma unroll 4
    for (int k = 0; k < KSEL; ++k) {
        const float* col = AdnT + (size_t)sidx[k] * DD;
        float v = sval[k];
        acc0 += v * col[t];
        acc1 += v * col[t + 256];
        acc2 += v * col[t + 512];
    }
    out[(size_t)row * DD + t] = acc0;
    out[(size_t)row * DD + t + 256] = acc1;
    out[(size_t)row * DD + t + 512] = acc2;
}

// ---------------------------------------------------------------------------
extern "C" void kernel_launch(void* const* d_in, const int* in_sizes, int n_in,
                              void* d_out, int out_size, void* d_ws, size_t ws_size,
                              hipStream_t stream) {
    const float* x  = (const float*)d_in[0];   // [B, D]
    const float* Ad = (const float*)d_in[1];   // [D, W]
    const float* bd = (const float*)d_in[2];   // [1, D]
    float* out = (float*)d_out;                // [B, D]

    const size_t ADNT_B = (size_t)WW * DD * 4;        // 25,165,824
    const size_t NRM_B  = (size_t)WW * 4;             // 32,768
    const size_t IDX_B  = (size_t)BBATCH * KSEL * 4;  // 1,048,576
    const size_t VAL_B  = IDX_B;
    const size_t G_B    = (size_t)WW * WW * 4;        // 268,435,456 (= 256 MiB)
    const size_t ZROW_B = (size_t)WW * 4;             // 32,768
    const size_t A_MIN  = ADNT_B + NRM_B + IDX_B + VAL_B + G_B + 128 * ZROW_B;

    if (ws_size >= A_MIN) {
        // ---------------- Layout A: everything in ws ----------------
        char* p = (char*)d_ws;
        float* AdnT = (float*)p;  p += ADNT_B;
        float* nrm  = (float*)p;  p += NRM_B;
        int*   idxL = (int*)p;    p += IDX_B;
        float* valL = (float*)p;  p += VAL_B;
        float* G    = (float*)p;  p += G_B;
        float* z    = (float*)p;
        size_t z_avail = ws_size - (ADNT_B + NRM_B + IDX_B + VAL_B + G_B);
        int chunk = (int)((z_avail / ZROW_B) / 128) * 128;
        if (chunk > BBATCH) chunk = BBATCH;

        colnorm_kernel<<<WW / 256, 256, 0, stream>>>(Ad, nrm);
        gram_tn_f32_kernel<<<dim3(WW / 64, WW / 128), 256, 0, stream>>>(Ad, nrm, G);
        mirror_kernel<<<dim3(WW / 64, WW / 64), 256, 0, stream>>>(G);
        for (int r0 = 0; r0 < BBATCH; r0 += chunk) {
            int rows = (BBATCH - r0 < chunk) ? (BBATCH - r0) : chunk;
            z_nn_f32_kernel<<<dim3(WW / 64, rows / 128), 256, 0, stream>>>(
                x + (size_t)r0 * DD, Ad, bd, nrm, z);
            mp_loop_kernel<<<rows, 256, 0, stream>>>(
                z, G, idxL + (size_t)r0 * KSEL, valL + (size_t)r0 * KSEL);
        }
        transpose_scale_kernel<<<dim3(WW / 32, DD / 32), dim3(32, 8), 0, stream>>>(Ad, nrm, AdnT);
        assemble_kernel<<<BBATCH, 256, 0, stream>>>(AdnT, bd, idxL, valL, out, 0);
    } else if (ws_size >= G_B) {
        // ---------------- Layout B: ws = G only; scratch in d_out ----------------
        // d_out carve (25,165,824 B total):
        //   [0 .. 20,971,520)          z chunks (512 rows x 32 KB used)
        //   [20,971,520 .. 21,004,288) nrm (32 KB)
        //   [23,068,672 .. 24,117,248) idxL [B,32]
        //   [24,117,248 .. 25,165,824) valL [B,32]
        float* G    = (float*)d_ws;
        char*  ob   = (char*)d_out;
        float* z    = (float*)ob;
        float* nrm  = (float*)(ob + 20971520);
        int*   idxL = (int*)(ob + 23068672);
        float* valL = (float*)(ob + 24117248);
        // after MP loops, G is dead -> reuse ws:
        float* AdnT = (float*)d_ws;
        int*   idx2 = (int*)((char*)d_ws + ADNT_B);
        float* val2 = (float*)((char*)d_ws + ADNT_B + IDX_B);
        const int chunk = 512;   // 4 x 128 rows -> 512 mp blocks = exactly 2/CU

        colnorm_kernel<<<WW / 256, 256, 0, stream>>>(Ad, nrm);
        gram_tn_f32_kernel<<<dim3(WW / 64, WW / 128), 256, 0, stream>>>(Ad, nrm, G);
        mirror_kernel<<<dim3(WW / 64, WW / 64), 256, 0, stream>>>(G);
        for (int r0 = 0; r0 < BBATCH; r0 += chunk) {
            int rows = (BBATCH - r0 < chunk) ? (BBATCH - r0) : chunk;
            z_nn_f32_kernel<<<dim3(WW / 64, rows / 128), 256, 0, stream>>>(
                x + (size_t)r0 * DD, Ad, bd, nrm, z);
            mp_loop_kernel<<<rows, 256, 0, stream>>>(
                z, G, idxL + (size_t)r0 * KSEL, valL + (size_t)r0 * KSEL);
        }
        {
            int n = BBATCH * KSEL;
            copy_meta_kernel<<<(n + 255) / 256, 256, 0, stream>>>(idxL, valL, idx2, val2, n);
        }
        transpose_scale_kernel<<<dim3(WW / 32, DD / 32), dim3(32, 8), 0, stream>>>(Ad, nrm, AdnT);
        assemble_kernel<<<BBATCH, 256, 0, stream>>>(AdnT, bd, idx2, val2, out, 0);
    }
    // else: ws too small for any fp32-G plan -> leave output zeroed (clean fail)
}